// Round 6
// baseline (273.941 us; speedup 1.0000x reference)
//
#include <hip/hip_runtime.h>
#include <math.h>

// ---- problem constants ----
#define BB 8
#define NN 1024
#define HEADC 8
#define SS 256
#define SCO 128
#define NE 16
#define C1 256
#define C2 512
#define C3 1024
#define NPTS (BB*NN)      // 8192
#define XCH (HEADC+SS)    // 264
#define K1P 192           // conv L1 K padded (136 -> 192)
#define BK 64

typedef unsigned short ushortT;
typedef __attribute__((ext_vector_type(8))) short bf16x8;   // 8 bf16 = 4 VGPRs
typedef __attribute__((ext_vector_type(4))) float f32x4;

// ---- workspace layout (byte offsets, all 256-aligned) ----
// h2 [8192][512]bf16 aliases XTB+HB (both dead by conv L2)
// dpC (8MB) aliases dpA+dpB (both dead before dec L3 runs)
#define OB_XTB    0ull          // ushort [8192][264]
#define OB_HB     4325376ull    // ushort [8192][256]  (bucket-ordered hidden)
#define OB_H2     0ull          // ushort [8192][512]
#define OB_XI     8519680ull    // ushort [8192][192]  (head 8 | routed 128 | pad 56)
#define OB_H1     11665408ull   // ushort [8192][256]
#define OB_WT1    15859712ull   // ushort [256][192]
#define OB_WT2    15958016ull   // ushort [512][256]
#define OB_WT3    16220160ull   // ushort [1024][512]
#define OB_W1T    17268736ull   // ushort [16][256][256]
#define OB_W2T    19365888ull   // ushort [16][128][256]
#define OB_PMAX   20414464ull   // float [64][1024]
#define OB_D1     20709376ull   // float [8][1024]
#define OB_D2     20742144ull   // float [8][2048]
#define OB_DPARTA 20807680ull   // float [64][8][1024]  (2 MB, dec L1 partials)
#define OB_DPARTB 22904832ull   // float [64][8][2048]  (4 MB, dec L2 partials)
#define OB_DPARTC 20807680ull   // float [32][8][8192]  (8 MB, aliases dpA/dpB)
#define OB_IDX    33390592ull   // int [8192]
#define OB_OFFS   33423360ull   // int [17]

__device__ __forceinline__ ushortT f2b(float f) {
  unsigned u = __float_as_uint(f);
  return (ushortT)((u + 0x7FFFu + ((u >> 16) & 1u)) >> 16);
}

// async global->LDS, 16B per lane. LDS dest must be wave-uniform base
// (+lane*16 implicit in HW); global src is per-lane.
__device__ __forceinline__ void gl16(const void* g, void* l) {
  __builtin_amdgcn_global_load_lds(
      (const __attribute__((address_space(1))) unsigned int*)g,
      (__attribute__((address_space(3))) unsigned int*)l, 16, 0, 0);
}

// ---------------------------------------------------------------------------
// Fused prep kernel: 4 roles by block range.
// ---------------------------------------------------------------------------
#define CW_S1 (256*192)
#define CW_S2 (512*256)
#define CW_S3 (1024*512)
#define PREP_P1 2304
#define PREP_P2 5056
#define PREP_P3 7104
#define PREP_GRID 7105

__global__ __launch_bounds__(256) void k_prep_all(
    const float* __restrict__ x, ushortT* __restrict__ xTb, ushortT* __restrict__ xi,
    const float* __restrict__ Wc1, const float* __restrict__ Wc2,
    const float* __restrict__ Wc3, ushortT* __restrict__ w1c,
    ushortT* __restrict__ w2c, ushortT* __restrict__ w3c,
    const float* __restrict__ W1, const float* __restrict__ W2,
    ushortT* __restrict__ W1tb, ushortT* __restrict__ W2tb,
    const int* __restrict__ cats, int* __restrict__ idx, int* __restrict__ offs) {
  __shared__ float t[32][33];
  __shared__ int cnt[NE], base[NE + 1], cur[NE];
  int bid = blockIdx.x;
  int tid = threadIdx.x;

  if (bid < PREP_P1) {
    int bx = bid & 31, by = (bid >> 5) % 9, bz = bid / 288;
    int n0 = bx * 32, c0 = by * 32;
    int tx = tid & 31, ty = tid >> 5;
    const float* s = x + (size_t)bz * XCH * NN;
    for (int yy = ty; yy < 32; yy += 8) {
      int c = c0 + yy;
      if (c < XCH) t[yy][tx] = s[(size_t)c * NN + n0 + tx];
    }
    __syncthreads();
    for (int yy = ty; yy < 32; yy += 8) {
      int n = n0 + yy, c = c0 + tx;
      if (c < XCH) {
        ushortT v = f2b(t[tx][yy]);
        xTb[(size_t)(bz * NN + n) * XCH + c] = v;
        if (c < HEADC) xi[(size_t)(bz * NN + n) * K1P + c] = v;
      }
    }
  } else if (bid < PREP_P2) {
    int i = (bid - PREP_P1) * 256 + tid;
    if (i < CW_S1) {
      int r = i / K1P, c = i - r * K1P;
      w1c[i] = (c < 136) ? f2b(Wc1[(size_t)r * 136 + c]) : (ushortT)0;
    } else if (i < CW_S1 + CW_S2) {
      int k = i - CW_S1;
      w2c[k] = f2b(Wc2[k]);
    } else if (i < CW_S1 + CW_S2 + CW_S3) {
      int k = i - CW_S1 - CW_S2;
      w3c[k] = f2b(Wc3[k]);
    }
  } else if (bid < PREP_P3) {
    int tt = bid - PREP_P2;
    int z = tt >> 6, ry = (tt >> 3) & 7, cx = tt & 7;
    const float* s;
    ushortT* d;
    int C;
    if (z < 16) { s = W1 + (size_t)z * 65536; d = W1tb + (size_t)z * 65536; C = 256; }
    else {
      if (cx >= 4) return;
      s = W2 + (size_t)(z - 16) * 32768; d = W2tb + (size_t)(z - 16) * 32768; C = 128;
    }
    int r0 = ry * 32, c0 = cx * 32;
    int tx = tid & 31, ty = tid >> 5;
    for (int yy = ty; yy < 32; yy += 8) {
      int r = r0 + yy, c = c0 + tx;
      if (c < C) t[yy][tx] = s[(size_t)r * C + c];
    }
    __syncthreads();
    for (int yy = ty; yy < 32; yy += 8) {
      int c = c0 + yy, r = r0 + tx;
      if (c < C) d[(size_t)c * 256 + r] = f2b(t[tx][yy]);
    }
  } else {
    if (tid < NE) cnt[tid] = 0;
    __syncthreads();
    for (int p = tid; p < NPTS; p += 256) atomicAdd(&cnt[cats[p]], 1);
    __syncthreads();
    if (tid == 0) {
      int s = 0;
      for (int e = 0; e < NE; ++e) { base[e] = s; cur[e] = s; s += cnt[e]; }
      base[NE] = s;
    }
    __syncthreads();
    for (int p = tid; p < NPTS; p += 256) {
      int pos = atomicAdd(&cur[cats[p]], 1);
      idx[pos] = p;
    }
    if (tid <= NE) offs[tid] = base[tid];
  }
}

// ---------------------------------------------------------------------------
// bf16 MFMA GEMM v2: 128x128 tile, 4 waves, BK=64, DOUBLE-BUFFERED LDS with
// global_load_lds(16B) staging, 2-phase schedule (issue next-tile loads BEFORE
// current-tile ds_read+MFMA; one barrier per tile — T3 minimum recipe).
// LDS layout linear; the XOR swizzle lives in the pre-swizzled GLOBAL source
// (slot^(row&7), an involution) and on the read side — rule 21 compliant.
// MODE 0: C_bf16 = maybe_relu(acc + bias)      (conv L1/L2)
// MODE 1: pmax[by][col] = colmax(acc) + bias   (conv L3)
// MODE 2: gather A via idx (xTb +8); C bucket-linear   (route L1)
// MODE 3: A bucket-linear; scatter C via idx (+8)      (route L2)
// ---------------------------------------------------------------------------
template<int MODE>
__global__ __launch_bounds__(256) void k_gemm(
    const ushortT* __restrict__ A, int lda,
    const ushortT* __restrict__ Bt, int ldb,
    const float* __restrict__ bias,
    ushortT* __restrict__ Cb, int ldc,
    float* __restrict__ pmaxOut,
    const int* __restrict__ idx, const int* __restrict__ offsp,
    int K, int relu) {
  __shared__ ushortT As[2][128 * BK];   // 2 x 16 KB
  __shared__ ushortT Bs[2][128 * BK];   // 2 x 16 KB
  __shared__ int pts[128];
  __shared__ float smax[2][128];
  int tid = threadIdx.x;
  int wave = tid >> 6, lane = tid & 63;
  int wm = wave >> 1, wn = wave & 1;
  int g = lane >> 4, lr = lane & 15;
  int n0 = blockIdx.x * 128;
  int m0 = 0, nr = 128, bucket0 = 0;

  if constexpr (MODE == 2 || MODE == 3) {
    int e = blockIdx.y, t = blockIdx.z;
    int s0 = offsp[e];
    int cnt = offsp[e + 1] - s0;
    int p0 = t * 128;
    if (p0 >= cnt) return;
    nr = min(128, cnt - p0);
    bucket0 = s0 + p0;
    Bt += (size_t)e * ((MODE == 2) ? 256 * 256 : 128 * 256);
    bias += e * ((MODE == 2) ? 256 : 128);
    if (tid < 128) pts[tid] = (tid < nr) ? idx[bucket0 + tid] : 0;
  } else {
    m0 = blockIdx.y * 128;
  }
  __syncthreads();   // pts visible before staging uses it

  // stage K-tile kt into buffer b (async; rows >= nr load row-0/in-bounds
  // garbage, whose outputs are never written)
  auto stage = [&](int b, int kt) {
    int k0 = kt * BK;
#pragma unroll
    for (int i = 0; i < 4; ++i) {
      int cbase = i * 256 + wave * 64;        // wave-uniform LDS slot base
      int c = cbase + lane;
      int row = c >> 3, p = c & 7;
      int sslot = p ^ (row & 7);              // pre-swizzled source chunk
      const ushortT* ga;
      if constexpr (MODE == 2) {
        ga = A + (size_t)pts[row] * lda + 8 + k0 + sslot * 8;
      } else if constexpr (MODE == 3) {
        ga = A + (size_t)(bucket0 + row) * lda + k0 + sslot * 8;
      } else {
        ga = A + (size_t)(m0 + row) * lda + k0 + sslot * 8;
      }
      gl16(ga, (void*)(As[b] + (size_t)cbase * 8));
      gl16(Bt + (size_t)(n0 + row) * ldb + k0 + sslot * 8,
           (void*)(Bs[b] + (size_t)cbase * 8));
    }
  };

  f32x4 acc[4][4];
#pragma unroll
  for (int mi = 0; mi < 4; ++mi)
#pragma unroll
    for (int nj = 0; nj < 4; ++nj) acc[mi][nj] = (f32x4)(0.f);

  int nkt = K / BK;
  stage(0, 0);
  __syncthreads();   // drains vmcnt -> tile 0 resident
  int buf = 0;
  for (int kt = 0; kt < nkt; ++kt) {
    if (kt + 1 < nkt) stage(buf ^ 1, kt + 1);   // async, hidden under MFMA
#pragma unroll
    for (int kk = 0; kk < 2; ++kk) {
      bf16x8 av[4], bv[4];
#pragma unroll
      for (int mi = 0; mi < 4; ++mi) {
        int row = wm * 64 + mi * 16 + lr;
        int slot = (kk * 4 + g) ^ (row & 7);
        av[mi] = *(const bf16x8*)(As[buf] + row * BK + slot * 8);
      }
#pragma unroll
      for (int nj = 0; nj < 4; ++nj) {
        int row = wn * 64 + nj * 16 + lr;
        int slot = (kk * 4 + g) ^ (row & 7);
        bv[nj] = *(const bf16x8*)(Bs[buf] + row * BK + slot * 8);
      }
#pragma unroll
      for (int mi = 0; mi < 4; ++mi)
#pragma unroll
        for (int nj = 0; nj < 4; ++nj)
          acc[mi][nj] = __builtin_amdgcn_mfma_f32_16x16x32_bf16(av[mi], bv[nj], acc[mi][nj], 0, 0, 0);
    }
    __syncthreads();   // drains this tile's async loads; guards buffer reuse
    buf ^= 1;
  }

  if constexpr (MODE == 1) {
#pragma unroll
    for (int nj = 0; nj < 4; ++nj) {
      float m = -INFINITY;
#pragma unroll
      for (int mi = 0; mi < 4; ++mi)
#pragma unroll
        for (int r = 0; r < 4; ++r) m = fmaxf(m, acc[mi][nj][r]);
      m = fmaxf(m, __shfl_xor(m, 16));
      m = fmaxf(m, __shfl_xor(m, 32));
      if (lane < 16) smax[wm][wn * 64 + nj * 16 + lr] = m;
    }
    __syncthreads();
    if (tid < 128) {
      float m = fmaxf(smax[0][tid], smax[1][tid]);
      pmaxOut[(size_t)blockIdx.y * C3 + n0 + tid] = m + bias[n0 + tid];
    }
  } else {
#pragma unroll
    for (int mi = 0; mi < 4; ++mi)
#pragma unroll
      for (int nj = 0; nj < 4; ++nj)
#pragma unroll
        for (int r = 0; r < 4; ++r) {
          int lrow = wm * 64 + mi * 16 + g * 4 + r;
          int col = n0 + wn * 64 + nj * 16 + lr;
          float v = acc[mi][nj][r] + bias[col];
          if (relu) v = fmaxf(v, 0.f);
          ushortT b = f2b(v);
          if constexpr (MODE == 0) {
            Cb[(size_t)(m0 + lrow) * ldc + col] = b;
          } else if constexpr (MODE == 2) {
            if (lrow < nr) Cb[(size_t)(bucket0 + lrow) * ldc + col] = b;
          } else {  // MODE 3
            if (lrow < nr) Cb[(size_t)pts[lrow] * ldc + 8 + col] = b;
          }
        }
  }
}

// ---------------------------------------------------------------------------
// Decoder partial GEMM, 3-deep rotating prefetch (24 x 16B in flight/wave).
// LMAX: A-staging computes latent = max over the 8 pmax m-tiles (fused
// latmax), and blockIdx.x==0 writes the latent slice to d_out tail.
// ---------------------------------------------------------------------------
template<int CHUNKLOG, int T, bool LMAX>
__global__ __launch_bounds__(T, 1) void k_dec(
    const float* __restrict__ Asrc, const float* __restrict__ W,
    float* __restrict__ part, float* __restrict__ outLat, int K, int N) {
  constexpr int CHUNK = 1 << CHUNKLOG;
  constexpr int G = CHUNK / 8;          // 8-row groups
  __shared__ float a[8 << CHUNKLOG];
  int i0 = blockIdx.y << CHUNKLOG;
  int tid = threadIdx.x;
  for (int idx = tid; idx < (8 << CHUNKLOG); idx += T) {
    int r = idx >> CHUNKLOG, i = idx & (CHUNK - 1);
    float v;
    if constexpr (LMAX) {
      v = -INFINITY;
#pragma unroll
      for (int t = 0; t < 8; ++t)
        v = fmaxf(v, Asrc[(size_t)((r << 3) + t) * K + i0 + i]);
      if (blockIdx.x == 0) outLat[(size_t)r * K + i0 + i] = v;
    } else {
      v = Asrc[(size_t)r * K + i0 + i];
    }
    a[idx] = v;
  }
  __syncthreads();

  int col = (blockIdx.x * T + tid) * 4;
  const float* wp = W + (size_t)i0 * N + col;
  f32x4 acc[8];
#pragma unroll
  for (int r = 0; r < 8; ++r) acc[r] = (f32x4)(0.f);

  f32x4 wreg[3][8];   // 96 VGPR rotating prefetch
#pragma unroll
  for (int gg = 0; gg < (G < 3 ? G : 3); ++gg)
#pragma unroll
    for (int q = 0; q < 8; ++q)
      wreg[gg][q] = *(const f32x4*)(wp + (size_t)(gg * 8 + q) * N);

#pragma unroll
  for (int gi = 0; gi < G; ++gi) {
    constexpr int B3[8] = {0, 1, 2, 0, 1, 2, 0, 1};
    const int b = B3[gi & 7];
#pragma unroll
    for (int r = 0; r < 8; ++r) {
      f32x4 av0 = *(const f32x4*)(&a[(r << CHUNKLOG) + gi * 8]);
      f32x4 av1 = *(const f32x4*)(&a[(r << CHUNKLOG) + gi * 8 + 4]);
      acc[r] += av0[0] * wreg[b][0] + av0[1] * wreg[b][1] +
                av0[2] * wreg[b][2] + av0[3] * wreg[b][3];
      acc[r] += av1[0] * wreg[b][4] + av1[1] * wreg[b][5] +
                av1[2] * wreg[b][6] + av1[3] * wreg[b][7];
    }
    if (gi + 3 < G) {
#pragma unroll
      for (int q = 0; q < 8; ++q)
        wreg[b][q] = *(const f32x4*)(wp + (size_t)((gi + 3) * 8 + q) * N);
    }
  }

  float* pp = part + (size_t)(blockIdx.y * 8) * N + col;
#pragma unroll
  for (int r = 0; r < 8; ++r) *(f32x4*)(pp + (size_t)r * N) = acc[r];
}

// reduce partials (f32x4): out[8][N] = relu?(bias + sum_kc part[kc][8][N])
__global__ __launch_bounds__(256) void k_reduce4(
    const float* __restrict__ part, const float* __restrict__ bias,
    float* __restrict__ out, int N, int KC, int doRelu) {
  int o4 = blockIdx.x * 256 + threadIdx.x;
  int col4 = o4 & ((N >> 2) - 1);
  f32x4 s = ((const f32x4*)bias)[col4];
  const f32x4* p4 = (const f32x4*)part;
#pragma unroll 8
  for (int kc = 0; kc < KC; ++kc)
    s += p4[(size_t)kc * 2 * N + o4];
  if (doRelu) {
#pragma unroll
    for (int r = 0; r < 4; ++r) s[r] = fmaxf(s[r], 0.f);
  }
  ((f32x4*)out)[o4] = s;
}

// ---------------------------------------------------------------------------
extern "C" void kernel_launch(void* const* d_in, const int* in_sizes, int n_in,
                              void* d_out, int out_size, void* d_ws, size_t ws_size,
                              hipStream_t stream) {
  const float* x    = (const float*)d_in[0];
  const int*   cats = (const int*)d_in[1];
  const float* W1   = (const float*)d_in[2];
  const float* b1   = (const float*)d_in[3];
  const float* W2   = (const float*)d_in[4];
  const float* b2   = (const float*)d_in[5];
  const float* Wc1  = (const float*)d_in[6];
  const float* bc1  = (const float*)d_in[7];
  const float* Wc2  = (const float*)d_in[8];
  const float* bc2  = (const float*)d_in[9];
  const float* Wc3  = (const float*)d_in[10];
  const float* bc3  = (const float*)d_in[11];
  const float* Wd1  = (const float*)d_in[12];
  const float* bd1  = (const float*)d_in[13];
  const float* Wd2  = (const float*)d_in[14];
  const float* bd2  = (const float*)d_in[15];
  const float* Wd3  = (const float*)d_in[16];
  const float* bd3  = (const float*)d_in[17];
  float* out = (float*)d_out;                 // [8*1024*8] out  then [8*1024] latent

  char* wsb = (char*)d_ws;
  ushortT* xTb  = (ushortT*)(wsb + OB_XTB);
  ushortT* hB   = (ushortT*)(wsb + OB_HB);
  ushortT* h2   = (ushortT*)(wsb + OB_H2);
  ushortT* xi   = (ushortT*)(wsb + OB_XI);
  ushortT* h1   = (ushortT*)(wsb + OB_H1);
  ushortT* Wt1b = (ushortT*)(wsb + OB_WT1);
  ushortT* Wt2b = (ushortT*)(wsb + OB_WT2);
  ushortT* Wt3b = (ushortT*)(wsb + OB_WT3);
  ushortT* W1tb = (ushortT*)(wsb + OB_W1T);
  ushortT* W2tb = (ushortT*)(wsb + OB_W2T);
  float* pmax   = (float*)(wsb + OB_PMAX);
  float* d1w    = (float*)(wsb + OB_D1);
  float* d2w    = (float*)(wsb + OB_D2);
  float* dpA    = (float*)(wsb + OB_DPARTA);
  float* dpB    = (float*)(wsb + OB_DPARTB);
  float* dpC    = (float*)(wsb + OB_DPARTC);
  int*   idx    = (int*)(wsb + OB_IDX);
  int*   offs   = (int*)(wsb + OB_OFFS);

  // ---- fused prep ----
  k_prep_all<<<PREP_GRID, 256, 0, stream>>>(
      x, xTb, xi, Wc1, Wc2, Wc3, Wt1b, Wt2b, Wt3b, W1, W2, W1tb, W2tb,
      cats, idx, offs);

  // ---- routing: 2 expert-batched MFMA GEMMs ----
  k_gemm<2><<<dim3(2, NE, 8), 256, 0, stream>>>(xTb, XCH, W1tb, 256, b1, hB, 256,
                                                nullptr, idx, offs, 256, 1);
  k_gemm<3><<<dim3(1, NE, 8), 256, 0, stream>>>(hB, 256, W2tb, 256, b2, xi, K1P,
                                                nullptr, idx, offs, 256, 0);

  // ---- conv stack (MFMA) + fused col-max ----
  k_gemm<0><<<dim3(2, 64), 256, 0, stream>>>(xi, K1P, Wt1b, K1P, bc1, h1, 256,
                                             nullptr, nullptr, nullptr, K1P, 1);
  k_gemm<0><<<dim3(4, 64), 256, 0, stream>>>(h1, 256, Wt2b, 256, bc2, h2, 512,
                                             nullptr, nullptr, nullptr, 256, 1);
  k_gemm<1><<<dim3(8, 64), 256, 0, stream>>>(h2, 512, Wt3b, 512, bc3, nullptr, 0,
                                             pmax, nullptr, nullptr, 512, 0);

  // ---- decoder (fp32, 3-deep prefetch; latmax fused into L1 staging) ----
  // L1: A = colmax(pmax), 1024x1024, chunk 16 -> grid (2,64)
  k_dec<4, 128, true><<<dim3(2, 64), 128, 0, stream>>>(pmax, Wd1, dpA,
                                                       out + 65536, 1024, 1024);
  k_reduce4<<<8, 256, 0, stream>>>(dpA, bd1, d1w, 1024, 64, 1);
  // L2: 1024x2048, chunk 16 -> grid (4,64)
  k_dec<4, 128, false><<<dim3(4, 64), 128, 0, stream>>>(d1w, Wd2, dpB,
                                                        nullptr, 1024, 2048);
  k_reduce4<<<16, 256, 0, stream>>>(dpB, bd2, d2w, 2048, 64, 1);
  // L3: 2048x8192, chunk 64 -> grid (8,32)
  k_dec<6, 256, false><<<dim3(8, 32), 256, 0, stream>>>(d2w, Wd3, dpC,
                                                        nullptr, 2048, 8192);
  k_reduce4<<<64, 256, 0, stream>>>(dpC, bd3, out, 8192, 32, 0);
  (void)in_sizes; (void)n_in; (void)out_size; (void)ws_size;
}

// Round 7
// 254.649 us; speedup vs baseline: 1.0758x; 1.0758x over previous
//
#include <hip/hip_runtime.h>
#include <math.h>

// ---- problem constants ----
#define BB 8
#define NN 1024
#define HEADC 8
#define SS 256
#define SCO 128
#define NE 16
#define C1 256
#define C2 512
#define C3 1024
#define NPTS (BB*NN)      // 8192
#define XCH (HEADC+SS)    // 264
#define K1P 192           // conv L1 K padded (136 -> 192)
#define BK 64

typedef unsigned short ushortT;
typedef __attribute__((ext_vector_type(8))) short bf16x8;   // 8 bf16 = 4 VGPRs
typedef __attribute__((ext_vector_type(4))) float f32x4;

// ---- workspace layout (byte offsets, all 256-aligned) ----
// h2 [8192][512]bf16 aliases XTB+HB (both dead by conv L2)
// dpC (16MB) aliases dpA/dpB (dead before dec L3); idx/offs live at 40MiB
#define OB_XTB    0ull          // ushort [8192][264]
#define OB_HB     4325376ull    // ushort [8192][256]  (bucket-ordered hidden)
#define OB_H2     0ull          // ushort [8192][512]
#define OB_XI     8519680ull    // ushort [8192][192]  (head 8 | routed 128 | pad 56)
#define OB_H1     11665408ull   // ushort [8192][256]
#define OB_WT1    15859712ull   // ushort [256][192]
#define OB_WT2    15958016ull   // ushort [512][256]
#define OB_WT3    16220160ull   // ushort [1024][512]
#define OB_W1T    17268736ull   // ushort [16][256][256]
#define OB_W2T    19365888ull   // ushort [16][128][256]
#define OB_PMAX   20414464ull   // float [64][1024]
#define OB_D1     20709376ull   // float [8][1024]
#define OB_D2     20742144ull   // float [8][2048]
#define OB_DPARTA 20807680ull   // float [64][8][1024]  (2 MB, dec L1 partials)
#define OB_DPARTB 22904832ull   // float [64][8][2048]  (4 MB, dec L2 partials)
#define OB_DPARTC 20807680ull   // float [64][8][8192]  (16 MB, aliases dpA/dpB)
#define OB_IDX    41943040ull   // int [8192]   (40 MiB — clear of dpC)
#define OB_OFFS   41975808ull   // int [17]

__device__ __forceinline__ ushortT f2b(float f) {
  unsigned u = __float_as_uint(f);
  return (ushortT)((u + 0x7FFFu + ((u >> 16) & 1u)) >> 16);
}

// async global->LDS, 16B per lane. LDS dest must be wave-uniform base
// (+lane*16 implicit in HW); global src is per-lane.
__device__ __forceinline__ void gl16(const void* g, void* l) {
  __builtin_amdgcn_global_load_lds(
      (const __attribute__((address_space(1))) unsigned int*)g,
      (__attribute__((address_space(3))) unsigned int*)l, 16, 0, 0);
}

// ---------------------------------------------------------------------------
// Fused prep kernel: 4 roles by block range.
// ---------------------------------------------------------------------------
#define CW_S1 (256*192)
#define CW_S2 (512*256)
#define CW_S3 (1024*512)
#define PREP_P1 2304
#define PREP_P2 5056
#define PREP_P3 7104
#define PREP_GRID 7105

__global__ __launch_bounds__(256) void k_prep_all(
    const float* __restrict__ x, ushortT* __restrict__ xTb, ushortT* __restrict__ xi,
    const float* __restrict__ Wc1, const float* __restrict__ Wc2,
    const float* __restrict__ Wc3, ushortT* __restrict__ w1c,
    ushortT* __restrict__ w2c, ushortT* __restrict__ w3c,
    const float* __restrict__ W1, const float* __restrict__ W2,
    ushortT* __restrict__ W1tb, ushortT* __restrict__ W2tb,
    const int* __restrict__ cats, int* __restrict__ idx, int* __restrict__ offs) {
  __shared__ float t[32][33];
  __shared__ int cnt[NE], base[NE + 1], cur[NE];
  int bid = blockIdx.x;
  int tid = threadIdx.x;

  if (bid < PREP_P1) {
    int bx = bid & 31, by = (bid >> 5) % 9, bz = bid / 288;
    int n0 = bx * 32, c0 = by * 32;
    int tx = tid & 31, ty = tid >> 5;
    const float* s = x + (size_t)bz * XCH * NN;
    for (int yy = ty; yy < 32; yy += 8) {
      int c = c0 + yy;
      if (c < XCH) t[yy][tx] = s[(size_t)c * NN + n0 + tx];
    }
    __syncthreads();
    for (int yy = ty; yy < 32; yy += 8) {
      int n = n0 + yy, c = c0 + tx;
      if (c < XCH) {
        ushortT v = f2b(t[tx][yy]);
        xTb[(size_t)(bz * NN + n) * XCH + c] = v;
        if (c < HEADC) xi[(size_t)(bz * NN + n) * K1P + c] = v;
      }
    }
  } else if (bid < PREP_P2) {
    int i = (bid - PREP_P1) * 256 + tid;
    if (i < CW_S1) {
      int r = i / K1P, c = i - r * K1P;
      w1c[i] = (c < 136) ? f2b(Wc1[(size_t)r * 136 + c]) : (ushortT)0;
    } else if (i < CW_S1 + CW_S2) {
      int k = i - CW_S1;
      w2c[k] = f2b(Wc2[k]);
    } else if (i < CW_S1 + CW_S2 + CW_S3) {
      int k = i - CW_S1 - CW_S2;
      w3c[k] = f2b(Wc3[k]);
    }
  } else if (bid < PREP_P3) {
    int tt = bid - PREP_P2;
    int z = tt >> 6, ry = (tt >> 3) & 7, cx = tt & 7;
    const float* s;
    ushortT* d;
    int C;
    if (z < 16) { s = W1 + (size_t)z * 65536; d = W1tb + (size_t)z * 65536; C = 256; }
    else {
      if (cx >= 4) return;
      s = W2 + (size_t)(z - 16) * 32768; d = W2tb + (size_t)(z - 16) * 32768; C = 128;
    }
    int r0 = ry * 32, c0 = cx * 32;
    int tx = tid & 31, ty = tid >> 5;
    for (int yy = ty; yy < 32; yy += 8) {
      int r = r0 + yy, c = c0 + tx;
      if (c < C) t[yy][tx] = s[(size_t)r * C + c];
    }
    __syncthreads();
    for (int yy = ty; yy < 32; yy += 8) {
      int c = c0 + yy, r = r0 + tx;
      if (c < C) d[(size_t)c * 256 + r] = f2b(t[tx][yy]);
    }
  } else {
    if (tid < NE) cnt[tid] = 0;
    __syncthreads();
    for (int p = tid; p < NPTS; p += 256) atomicAdd(&cnt[cats[p]], 1);
    __syncthreads();
    if (tid == 0) {
      int s = 0;
      for (int e = 0; e < NE; ++e) { base[e] = s; cur[e] = s; s += cnt[e]; }
      base[NE] = s;
    }
    __syncthreads();
    for (int p = tid; p < NPTS; p += 256) {
      int pos = atomicAdd(&cur[cats[p]], 1);
      idx[pos] = p;
    }
    if (tid <= NE) offs[tid] = base[tid];
  }
}

// ---------------------------------------------------------------------------
// bf16 MFMA GEMM v2: 128x128 tile, 4 waves, BK=64, double-buffered LDS,
// global_load_lds(16B) staging, 2-phase schedule. Pre-swizzled global source
// (slot^(row&7) involution), linear LDS dest, XOR on read — rule 21.
// ---------------------------------------------------------------------------
template<int MODE>
__global__ __launch_bounds__(256) void k_gemm(
    const ushortT* __restrict__ A, int lda,
    const ushortT* __restrict__ Bt, int ldb,
    const float* __restrict__ bias,
    ushortT* __restrict__ Cb, int ldc,
    float* __restrict__ pmaxOut,
    const int* __restrict__ idx, const int* __restrict__ offsp,
    int K, int relu) {
  __shared__ ushortT As[2][128 * BK];
  __shared__ ushortT Bs[2][128 * BK];
  __shared__ int pts[128];
  __shared__ float smax[2][128];
  int tid = threadIdx.x;
  int wave = tid >> 6, lane = tid & 63;
  int wm = wave >> 1, wn = wave & 1;
  int g = lane >> 4, lr = lane & 15;
  int n0 = blockIdx.x * 128;
  int m0 = 0, nr = 128, bucket0 = 0;

  if constexpr (MODE == 2 || MODE == 3) {
    int e = blockIdx.y, t = blockIdx.z;
    int s0 = offsp[e];
    int cnt = offsp[e + 1] - s0;
    int p0 = t * 128;
    if (p0 >= cnt) return;
    nr = min(128, cnt - p0);
    bucket0 = s0 + p0;
    Bt += (size_t)e * ((MODE == 2) ? 256 * 256 : 128 * 256);
    bias += e * ((MODE == 2) ? 256 : 128);
    if (tid < 128) pts[tid] = (tid < nr) ? idx[bucket0 + tid] : 0;
  } else {
    m0 = blockIdx.y * 128;
  }
  __syncthreads();   // pts visible before staging uses it

  auto stage = [&](int b, int kt) {
    int k0 = kt * BK;
#pragma unroll
    for (int i = 0; i < 4; ++i) {
      int cbase = i * 256 + wave * 64;        // wave-uniform LDS slot base
      int c = cbase + lane;
      int row = c >> 3, p = c & 7;
      int sslot = p ^ (row & 7);              // pre-swizzled source chunk
      const ushortT* ga;
      if constexpr (MODE == 2) {
        ga = A + (size_t)pts[row] * lda + 8 + k0 + sslot * 8;
      } else if constexpr (MODE == 3) {
        ga = A + (size_t)(bucket0 + row) * lda + k0 + sslot * 8;
      } else {
        ga = A + (size_t)(m0 + row) * lda + k0 + sslot * 8;
      }
      gl16(ga, (void*)(As[b] + (size_t)cbase * 8));
      gl16(Bt + (size_t)(n0 + row) * ldb + k0 + sslot * 8,
           (void*)(Bs[b] + (size_t)cbase * 8));
    }
  };

  f32x4 acc[4][4];
#pragma unroll
  for (int mi = 0; mi < 4; ++mi)
#pragma unroll
    for (int nj = 0; nj < 4; ++nj) acc[mi][nj] = (f32x4)(0.f);

  int nkt = K / BK;
  stage(0, 0);
  __syncthreads();
  int buf = 0;
  for (int kt = 0; kt < nkt; ++kt) {
    if (kt + 1 < nkt) stage(buf ^ 1, kt + 1);   // async, hidden under MFMA
#pragma unroll
    for (int kk = 0; kk < 2; ++kk) {
      bf16x8 av[4], bv[4];
#pragma unroll
      for (int mi = 0; mi < 4; ++mi) {
        int row = wm * 64 + mi * 16 + lr;
        int slot = (kk * 4 + g) ^ (row & 7);
        av[mi] = *(const bf16x8*)(As[buf] + row * BK + slot * 8);
      }
#pragma unroll
      for (int nj = 0; nj < 4; ++nj) {
        int row = wn * 64 + nj * 16 + lr;
        int slot = (kk * 4 + g) ^ (row & 7);
        bv[nj] = *(const bf16x8*)(Bs[buf] + row * BK + slot * 8);
      }
#pragma unroll
      for (int mi = 0; mi < 4; ++mi)
#pragma unroll
        for (int nj = 0; nj < 4; ++nj)
          acc[mi][nj] = __builtin_amdgcn_mfma_f32_16x16x32_bf16(av[mi], bv[nj], acc[mi][nj], 0, 0, 0);
    }
    __syncthreads();
    buf ^= 1;
  }

  if constexpr (MODE == 1) {
#pragma unroll
    for (int nj = 0; nj < 4; ++nj) {
      float m = -INFINITY;
#pragma unroll
      for (int mi = 0; mi < 4; ++mi)
#pragma unroll
        for (int r = 0; r < 4; ++r) m = fmaxf(m, acc[mi][nj][r]);
      m = fmaxf(m, __shfl_xor(m, 16));
      m = fmaxf(m, __shfl_xor(m, 32));
      if (lane < 16) smax[wm][wn * 64 + nj * 16 + lr] = m;
    }
    __syncthreads();
    if (tid < 128) {
      float m = fmaxf(smax[0][tid], smax[1][tid]);
      pmaxOut[(size_t)blockIdx.y * C3 + n0 + tid] = m + bias[n0 + tid];
    }
  } else {
#pragma unroll
    for (int mi = 0; mi < 4; ++mi)
#pragma unroll
      for (int nj = 0; nj < 4; ++nj)
#pragma unroll
        for (int r = 0; r < 4; ++r) {
          int lrow = wm * 64 + mi * 16 + g * 4 + r;
          int col = n0 + wn * 64 + nj * 16 + lr;
          float v = acc[mi][nj][r] + bias[col];
          if (relu) v = fmaxf(v, 0.f);
          ushortT b = f2b(v);
          if constexpr (MODE == 0) {
            Cb[(size_t)(m0 + lrow) * ldc + col] = b;
          } else if constexpr (MODE == 2) {
            if (lrow < nr) Cb[(size_t)(bucket0 + lrow) * ldc + col] = b;
          } else {  // MODE 3
            if (lrow < nr) Cb[(size_t)pts[lrow] * ldc + 8 + col] = b;
          }
        }
  }
}

// ---------------------------------------------------------------------------
// Decoder partial GEMM, 2-deep wa/wb prefetch (round-5 proven: ~130 VGPR, no
// spill — round-6's 3-deep hit the 256-VGPR cap and spilled to scratch).
// Latency hiding now comes from TLP: k-split sized for >=512 blocks on L3.
// LMAX: A-staging computes latent = max over 8 pmax m-tiles; blockIdx.x==0
// writes the latent slice to d_out tail.
// ---------------------------------------------------------------------------
template<int CHUNKLOG, int T, bool LMAX>
__global__ __launch_bounds__(T, 1) void k_dec(
    const float* __restrict__ Asrc, const float* __restrict__ W,
    float* __restrict__ part, float* __restrict__ outLat, int K, int N) {
  constexpr int CHUNK = 1 << CHUNKLOG;   // >= 16, multiple of 16
  __shared__ float a[8 << CHUNKLOG];
  int i0 = blockIdx.y << CHUNKLOG;
  int tid = threadIdx.x;
  for (int idx = tid; idx < (8 << CHUNKLOG); idx += T) {
    int r = idx >> CHUNKLOG, i = idx & (CHUNK - 1);
    float v;
    if constexpr (LMAX) {
      v = -INFINITY;
#pragma unroll
      for (int t = 0; t < 8; ++t)
        v = fmaxf(v, Asrc[(size_t)((r << 3) + t) * K + i0 + i]);
      if (blockIdx.x == 0) outLat[(size_t)r * K + i0 + i] = v;
    } else {
      v = Asrc[(size_t)r * K + i0 + i];
    }
    a[idx] = v;
  }
  __syncthreads();

  int col = (blockIdx.x * T + tid) * 4;
  const float* wp = W + (size_t)i0 * N + col;
  f32x4 acc[8];
#pragma unroll
  for (int r = 0; r < 8; ++r) acc[r] = (f32x4)(0.f);

  f32x4 wa[8], wb[8];
#pragma unroll
  for (int q = 0; q < 8; ++q) wa[q] = *(const f32x4*)(wp + (size_t)q * N);
#pragma unroll
  for (int q = 0; q < 8; ++q) wb[q] = *(const f32x4*)(wp + (size_t)(8 + q) * N);

#pragma unroll
  for (int k0 = 0; k0 < CHUNK; k0 += 16) {
#pragma unroll
    for (int r = 0; r < 8; ++r) {
      f32x4 av0 = *(const f32x4*)(&a[(r << CHUNKLOG) + k0]);
      f32x4 av1 = *(const f32x4*)(&a[(r << CHUNKLOG) + k0 + 4]);
      acc[r] += av0[0] * wa[0] + av0[1] * wa[1] + av0[2] * wa[2] + av0[3] * wa[3];
      acc[r] += av1[0] * wa[4] + av1[1] * wa[5] + av1[2] * wa[6] + av1[3] * wa[7];
    }
    if (k0 + 16 < CHUNK) {
#pragma unroll
      for (int q = 0; q < 8; ++q) wa[q] = *(const f32x4*)(wp + (size_t)(k0 + 16 + q) * N);
    }
#pragma unroll
    for (int r = 0; r < 8; ++r) {
      f32x4 av0 = *(const f32x4*)(&a[(r << CHUNKLOG) + k0 + 8]);
      f32x4 av1 = *(const f32x4*)(&a[(r << CHUNKLOG) + k0 + 12]);
      acc[r] += av0[0] * wb[0] + av0[1] * wb[1] + av0[2] * wb[2] + av0[3] * wb[3];
      acc[r] += av1[0] * wb[4] + av1[1] * wb[5] + av1[2] * wb[6] + av1[3] * wb[7];
    }
    if (k0 + 24 < CHUNK) {
#pragma unroll
      for (int q = 0; q < 8; ++q) wb[q] = *(const f32x4*)(wp + (size_t)(k0 + 24 + q) * N);
    }
  }

  float* pp = part + (size_t)(blockIdx.y * 8) * N + col;
#pragma unroll
  for (int r = 0; r < 8; ++r) *(f32x4*)(pp + (size_t)r * N) = acc[r];
}

// reduce partials (f32x4): out[8][N] = relu?(bias + sum_kc part[kc][8][N])
__global__ __launch_bounds__(256) void k_reduce4(
    const float* __restrict__ part, const float* __restrict__ bias,
    float* __restrict__ out, int N, int KC, int doRelu) {
  int o4 = blockIdx.x * 256 + threadIdx.x;
  int col4 = o4 & ((N >> 2) - 1);
  f32x4 s = ((const f32x4*)bias)[col4];
  const f32x4* p4 = (const f32x4*)part;
#pragma unroll 8
  for (int kc = 0; kc < KC; ++kc)
    s += p4[(size_t)kc * 2 * N + o4];
  if (doRelu) {
#pragma unroll
    for (int r = 0; r < 4; ++r) s[r] = fmaxf(s[r], 0.f);
  }
  ((f32x4*)out)[o4] = s;
}

// ---------------------------------------------------------------------------
extern "C" void kernel_launch(void* const* d_in, const int* in_sizes, int n_in,
                              void* d_out, int out_size, void* d_ws, size_t ws_size,
                              hipStream_t stream) {
  const float* x    = (const float*)d_in[0];
  const int*   cats = (const int*)d_in[1];
  const float* W1   = (const float*)d_in[2];
  const float* b1   = (const float*)d_in[3];
  const float* W2   = (const float*)d_in[4];
  const float* b2   = (const float*)d_in[5];
  const float* Wc1  = (const float*)d_in[6];
  const float* bc1  = (const float*)d_in[7];
  const float* Wc2  = (const float*)d_in[8];
  const float* bc2  = (const float*)d_in[9];
  const float* Wc3  = (const float*)d_in[10];
  const float* bc3  = (const float*)d_in[11];
  const float* Wd1  = (const float*)d_in[12];
  const float* bd1  = (const float*)d_in[13];
  const float* Wd2  = (const float*)d_in[14];
  const float* bd2  = (const float*)d_in[15];
  const float* Wd3  = (const float*)d_in[16];
  const float* bd3  = (const float*)d_in[17];
  float* out = (float*)d_out;                 // [8*1024*8] out  then [8*1024] latent

  char* wsb = (char*)d_ws;
  ushortT* xTb  = (ushortT*)(wsb + OB_XTB);
  ushortT* hB   = (ushortT*)(wsb + OB_HB);
  ushortT* h2   = (ushortT*)(wsb + OB_H2);
  ushortT* xi   = (ushortT*)(wsb + OB_XI);
  ushortT* h1   = (ushortT*)(wsb + OB_H1);
  ushortT* Wt1b = (ushortT*)(wsb + OB_WT1);
  ushortT* Wt2b = (ushortT*)(wsb + OB_WT2);
  ushortT* Wt3b = (ushortT*)(wsb + OB_WT3);
  ushortT* W1tb = (ushortT*)(wsb + OB_W1T);
  ushortT* W2tb = (ushortT*)(wsb + OB_W2T);
  float* pmax   = (float*)(wsb + OB_PMAX);
  float* d1w    = (float*)(wsb + OB_D1);
  float* d2w    = (float*)(wsb + OB_D2);
  float* dpA    = (float*)(wsb + OB_DPARTA);
  float* dpB    = (float*)(wsb + OB_DPARTB);
  float* dpC    = (float*)(wsb + OB_DPARTC);
  int*   idx    = (int*)(wsb + OB_IDX);
  int*   offs   = (int*)(wsb + OB_OFFS);

  // ---- fused prep ----
  k_prep_all<<<PREP_GRID, 256, 0, stream>>>(
      x, xTb, xi, Wc1, Wc2, Wc3, Wt1b, Wt2b, Wt3b, W1, W2, W1tb, W2tb,
      cats, idx, offs);

  // ---- routing: 2 expert-batched MFMA GEMMs ----
  k_gemm<2><<<dim3(2, NE, 8), 256, 0, stream>>>(xTb, XCH, W1tb, 256, b1, hB, 256,
                                                nullptr, idx, offs, 256, 1);
  k_gemm<3><<<dim3(1, NE, 8), 256, 0, stream>>>(hB, 256, W2tb, 256, b2, xi, K1P,
                                                nullptr, idx, offs, 256, 0);

  // ---- conv stack (MFMA) + fused col-max ----
  k_gemm<0><<<dim3(2, 64), 256, 0, stream>>>(xi, K1P, Wt1b, K1P, bc1, h1, 256,
                                             nullptr, nullptr, nullptr, K1P, 1);
  k_gemm<0><<<dim3(4, 64), 256, 0, stream>>>(h1, 256, Wt2b, 256, bc2, h2, 512,
                                             nullptr, nullptr, nullptr, 256, 1);
  k_gemm<1><<<dim3(8, 64), 256, 0, stream>>>(h2, 512, Wt3b, 512, bc3, nullptr, 0,
                                             pmax, nullptr, nullptr, 512, 0);

  // ---- decoder (fp32, 2-deep prefetch + high TLP; latmax fused into L1) ----
  // L1: A = colmax(pmax), 1024x1024, chunk 16 -> grid (2,64) = 128 blocks
  k_dec<4, 128, true><<<dim3(2, 64), 128, 0, stream>>>(pmax, Wd1, dpA,
                                                       out + 65536, 1024, 1024);
  k_reduce4<<<8, 256, 0, stream>>>(dpA, bd1, d1w, 1024, 64, 1);
  // L2: 1024x2048, chunk 16 -> grid (4,64) = 256 blocks
  k_dec<4, 128, false><<<dim3(4, 64), 128, 0, stream>>>(d1w, Wd2, dpB,
                                                        nullptr, 1024, 2048);
  k_reduce4<<<16, 256, 0, stream>>>(dpB, bd2, d2w, 2048, 64, 1);
  // L3: 2048x8192, chunk 32 -> grid (8,64) = 512 blocks (8 waves/CU)
  k_dec<5, 256, false><<<dim3(8, 64), 256, 0, stream>>>(d2w, Wd3, dpC,
                                                        nullptr, 2048, 8192);
  k_reduce4<<<64, 256, 0, stream>>>(dpC, bd3, out, 8192, 64, 0);
  (void)in_sizes; (void)n_in; (void)out_size; (void)ws_size;
}